// Round 21
// baseline (56.100 us; speedup 1.0000x reference)
//
#include <hip/hip_runtime.h>
#include <hip/hip_bf16.h>
#include <cstdint>

#define EPS 1e-5f

typedef short bf16x8 __attribute__((ext_vector_type(8)));
typedef float f32x16 __attribute__((ext_vector_type(16)));
typedef unsigned int u32x4 __attribute__((ext_vector_type(4)));

// ws float-offsets
#define WS_TW1S 0        // 16384 ushort: chi-permuted GEMM2 A-frag layout
#define WS_FWQ  8192     // 8192 ushort: GEMM1 A-frag layout
#define WS_FBQ  12800    // 64 floats (unused by main now, kept for layout stability)
#define WS_C2   12864    // 8 floats
#define WS_TB1V 12880    // 256 ushort: [r*8 + th] bf16 tb1s
#define WS_W2A  13056    // 2048 ushort: [((part*2+kt)*2+hi)*32+ln]*8 w2 A-frags
#define WS_FBA  14080    // 2048 ushort: [((ht*2+hh)*32+r)*8+e] GEMM1 bias A-frags

static __device__ __forceinline__ unsigned short f2bf(float f) {
    unsigned int u = __float_as_uint(f);
    u += 0x7fffu + ((u >> 16) & 1u);   // RNE
    return (unsigned short)(u >> 16);
}
static __device__ __forceinline__ short f2bf_fast(float f) {
    __hip_bfloat16 b = __float2bfloat16(f);
    return __builtin_bit_cast(short, b);
}
static __device__ __forceinline__ unsigned pk_bf16(float lo, float hi) {
    unsigned l = (unsigned)(unsigned short)__builtin_bit_cast(unsigned short, __float2bfloat16(lo));
    unsigned h = (unsigned)(unsigned short)__builtin_bit_cast(unsigned short, __float2bfloat16(hi));
    return l | (h << 16);
}

// chi  (GEMM1->GEMM2): j = ht*32+qq*8+4h+m -> ks = ht*2+(qq>>1), slot = 8h+(qq&1)*4+m
// chi2 (z->epilogue):  r = (e&3) + 8*((e>>2)&1) + 16*kt + 4*hi at slot 8*hi+e
__global__ void tarnet_pre(
    const float* __restrict__ fw, const float* __restrict__ fb,
    const float* __restrict__ f_gamma, const float* __restrict__ f_beta,
    const float* __restrict__ f_mean,  const float* __restrict__ f_var,
    const float* __restrict__ tw1, const float* __restrict__ tb1,
    const float* __restrict__ t_gamma, const float* __restrict__ t_beta,
    const float* __restrict__ t_mean,  const float* __restrict__ t_var,
    const float* __restrict__ tw2, const float* __restrict__ tb2,
    float* __restrict__ ws)
{
    __shared__ float fs[64], fsh[64];
    const int i = threadIdx.x;  // 256 threads
    if (i < 64) {
        float s = f_gamma[i] * rsqrtf(f_var[i] + EPS);
        fs[i]  = s;
        fsh[i] = f_beta[i] - f_mean[i] * s;
    }
    __syncthreads();

    unsigned short* tw1s_u = (unsigned short*)(ws + WS_TW1S);
    unsigned short* fwq_u  = (unsigned short*)(ws + WS_FWQ);
    unsigned short* tb1v_u = (unsigned short*)(ws + WS_TB1V);
    unsigned short* w2a_u  = (unsigned short*)(ws + WS_W2A);
    unsigned short* fba_u  = (unsigned short*)(ws + WS_FBA);

    if (blockIdx.x == 0) {
        const int t = i >> 5, r = i & 31;
        const int idx = t * 32 + r;
        float tsc  = t_gamma[idx] * rsqrtf(t_var[idx] + EPS);
        float tb1s = tb1[idx];
        for (int j = 0; j < 64; ++j) {
            float w = tw1[idx * 64 + j];
            tb1s += w * fsh[j];
            int ht = j >> 5, qq = (j >> 3) & 3, h = (j >> 2) & 1, m = j & 3;
            int ks = ht * 2 + (qq >> 1);
            int ep = (qq & 1) * 4 + m;
            tw1s_u[(((t*4 + ks)*2 + h)*32 + r)*8 + ep] = f2bf(w * fs[j]);
        }
        tb1v_u[r*8 + t] = f2bf(tb1s);
        if (r == 0) {
            float a = tb2[t];
            for (int rr = 0; rr < 32; ++rr) {
                int id2 = t*32 + rr;
                float ts2 = t_gamma[id2] * rsqrtf(t_var[id2] + EPS);
                a += tw2[id2] * (t_beta[id2] - ts2 * t_mean[id2]);
            }
            ws[WS_C2 + t] = a;
        }
    } else {
        {   // fw conversion, frag-native
            const int hc = i >> 2, kq = (i & 3) * 32;
            for (int kk = 0; kk < 32; ++kk) {
                const int k = kq + kk;
                const int ks = k >> 4, h = (k >> 3) & 1, jj = k & 7;
                fwq_u[(((ks*2 + h)*64) + hc)*8 + jj] = f2bf(fw[hc*128 + k]);
            }
        }
        {   // FBA: GEMM1 bias A-frags — fb[row] at K-slot0 (hh==0 lanes, e==0)
            if (i < 128) {
                const int r = i & 31, hh = (i >> 5) & 1, ht = (i >> 6) & 1;
                const int base = ((ht*2 + hh)*32 + r)*8;
                for (int e = 0; e < 8; ++e)
                    fba_u[base + e] = (e == 0 && hh == 0) ? f2bf(fb[ht*32 + r]) : 0;
            }
        }
        {   // W2A: epilogue A-frags (R12-validated)
            const int ln = i & 31, hh = (i >> 5) & 1, kt = (i >> 6) & 1, part = i >> 7;
            const int base = (((part*2 + kt)*2 + hh)*32 + ln)*8;
            for (int e = 0; e < 8; ++e) {
                unsigned short v = 0;
                if (ln < 8) {
                    const int rr = (e & 3) + 8*((e >> 2) & 1) + 16*kt + 4*hh;
                    const int id2 = ln*32 + rr;
                    float tsc = t_gamma[id2] * rsqrtf(t_var[id2] + EPS);
                    float w = tw2[id2] * tsc;
                    if (part == 0) v = f2bf(w);
                    else {
                        float whi = __uint_as_float(((unsigned)f2bf(w)) << 16);
                        v = f2bf(w - whi);
                    }
                }
                w2a_u[base + e] = v;
            }
        }
    }
}

// 4 waves/block, 128-sample tile, 32 KB LDS; all biases via MFMA; 4 waves/SIMD.
__global__ __launch_bounds__(256, 4) void tarnet_main(
    const float* __restrict__ x, const int* __restrict__ t_arr,
    const float* __restrict__ ws, float* __restrict__ out)
{
    __shared__ unsigned short x_lds_u[128 * 128];   // 32 KB bf16, XOR-swizzled
    char* xl = (char*)x_lds_u;

    const int tid  = threadIdx.x;
    const int wave = tid >> 6, lane = tid & 63;
    const int ln31 = lane & 31, hi = lane >> 5;
    const int sbase = blockIdx.x * 128;

    {   // coalesced stage: 8 pair-iters x 32 B/lane contiguous (R8-validated)
        const float4* xg = (const float4*)(x + (size_t)sbase * 128);
#pragma unroll
        for (int it = 0; it < 8; ++it) {
            const int i = it * 256 + tid;
            float4 a = xg[2*i], b = xg[2*i + 1];
            bf16x8 v;
            v[0] = f2bf_fast(a.x); v[1] = f2bf_fast(a.y);
            v[2] = f2bf_fast(a.z); v[3] = f2bf_fast(a.w);
            v[4] = f2bf_fast(b.x); v[5] = f2bf_fast(b.y);
            v[6] = f2bf_fast(b.z); v[7] = f2bf_fast(b.w);
            const int row = i >> 4, pcol = i & 15;
            *(bf16x8*)(xl + row * 256 + ((pcol * 16) ^ ((row & 15) << 4))) = v;
        }
    }
    __syncthreads();

    const unsigned short* fwq_u  = (const unsigned short*)(ws + WS_FWQ);
    const unsigned short* tw1s_u = (const unsigned short*)(ws + WS_TW1S);
    const unsigned short* w2a_u  = (const unsigned short*)(ws + WS_W2A);
    const unsigned short* fba_u  = (const unsigned short*)(ws + WS_FBA);

    // wave-invariant tables
    bf16x8 w2f[4];
#pragma unroll
    for (int pk = 0; pk < 4; ++pk)
        w2f[pk] = *(const bf16x8*)(w2a_u + ((pk*2 + hi)*32 + ln31)*8);
    const bf16x8 tb1v = *(const bf16x8*)((const unsigned short*)(ws + WS_TB1V) + ln31*8);
    bf16x8 fba[2];
#pragma unroll
    for (int ht = 0; ht < 2; ++ht)
        fba[ht] = *(const bf16x8*)(fba_u + ((ht*2 + hi)*32 + ln31)*8);
    u32x4 hbv = { hi ? 0u : 0x3F80u, 0u, 0u, 0u };   // const-1 B-frag, slot0
    const bf16x8 hbias = __builtin_bit_cast(bf16x8, hbv);

    const int tsel = t_arr[sbase + wave * 32 + ln31];
    const int srow = wave * 32 + ln31;
    const int rb = srow * 256, swz = (srow & 15) << 4;

    // ---- GEMM1: h^T = fw @ x^T; fb via bias-MFMA ----
    f32x16 acc[2] = {{0.f}, {0.f}};
#pragma unroll
    for (int ks = 0; ks < 8; ++ks) {
        bf16x8 wa0 = *(const bf16x8*)(fwq_u + (((ks*2 + hi)*64) + ln31     )*8);
        bf16x8 wa1 = *(const bf16x8*)(fwq_u + (((ks*2 + hi)*64) + ln31 + 32)*8);
        bf16x8 xf  = *(const bf16x8*)(xl + rb + ((ks*32 + hi*16) ^ swz));
        acc[0] = __builtin_amdgcn_mfma_f32_32x32x16_bf16(wa0, xf, acc[0], 0, 0, 0);
        acc[1] = __builtin_amdgcn_mfma_f32_32x32x16_bf16(wa1, xf, acc[1], 0, 0, 0);
    }
    acc[0] = __builtin_amdgcn_mfma_f32_32x32x16_bf16(fba[0], hbias, acc[0], 0, 0, 0);
    acc[1] = __builtin_amdgcn_mfma_f32_32x32x16_bf16(fba[1], hbias, acc[1], 0, 0, 0);

    // ---- relu -> chi-pack: lane-local GEMM2 B-frags ----
    bf16x8 hb[4];
    {
        unsigned w0[2][4], w1[2][4];
#pragma unroll
        for (int ht = 0; ht < 2; ++ht)
#pragma unroll
            for (int qq = 0; qq < 4; ++qq) {
                float a0 = fmaxf(acc[ht][qq*4+0], 0.f);
                float a1 = fmaxf(acc[ht][qq*4+1], 0.f);
                float a2 = fmaxf(acc[ht][qq*4+2], 0.f);
                float a3 = fmaxf(acc[ht][qq*4+3], 0.f);
                w0[ht][qq] = pk_bf16(a0, a1);
                w1[ht][qq] = pk_bf16(a2, a3);
            }
#pragma unroll
        for (int ks = 0; ks < 4; ++ks) {
            const int ht = ks >> 1, qa = (ks & 1) * 2;
            u32x4 wv = {w0[ht][qa], w1[ht][qa], w0[ht][qa+1], w1[ht][qa+1]};
            hb[ks] = __builtin_bit_cast(bf16x8, wv);
        }
    }

    // ---- GEMM2 dense 8 heads, single chains (TLP hides latency at 4 w/SIMD) ----
    float outv = 0.f;
#pragma unroll
    for (int th = 0; th < 8; ++th) {
        f32x16 z = {0.f};
#pragma unroll
        for (int ks = 0; ks < 4; ++ks) {
            bf16x8 aw = *(const bf16x8*)(tw1s_u + (((th*4 + ks)*2 + hi)*32 + ln31)*8);
            z = __builtin_amdgcn_mfma_f32_32x32x16_bf16(aw, hb[ks], z, 0, 0, 0);
        }
        u32x4 tbv = { hi ? 0u : (unsigned)(unsigned short)tb1v[th], 0u, 0u, 0u };
        z = __builtin_amdgcn_mfma_f32_32x32x16_bf16(
                __builtin_bit_cast(bf16x8, tbv), hbias, z, 0, 0, 0);

        bf16x8 zb[2];
#pragma unroll
        for (int kt = 0; kt < 2; ++kt) {
            u32x4 wv;
#pragma unroll
            for (int wd = 0; wd < 4; ++wd)
                wv[wd] = pk_bf16(fmaxf(z[8*kt + 2*wd], 0.f),
                                 fmaxf(z[8*kt + 2*wd + 1], 0.f));
            zb[kt] = __builtin_bit_cast(bf16x8, wv);
        }
        f32x16 d = {0.f};
        d = __builtin_amdgcn_mfma_f32_32x32x16_bf16(w2f[0], zb[0], d, 0, 0, 0);
        d = __builtin_amdgcn_mfma_f32_32x32x16_bf16(w2f[1], zb[1], d, 0, 0, 0);
        d = __builtin_amdgcn_mfma_f32_32x32x16_bf16(w2f[2], zb[0], d, 0, 0, 0);
        d = __builtin_amdgcn_mfma_f32_32x32x16_bf16(w2f[3], zb[1], d, 0, 0, 0);

        float cand  = d[th & 3];
        float other = __shfl_xor(cand, 32);
        float val   = (hi == (th >> 2)) ? cand : other;
        outv = (th == tsel) ? val : outv;
    }
    outv += ws[WS_C2 + tsel];
    if (!hi) out[sbase + wave * 32 + ln31] = outv;
}

extern "C" void kernel_launch(void* const* d_in, const int* in_sizes, int n_in,
                              void* d_out, int out_size, void* d_ws, size_t ws_size,
                              hipStream_t stream) {
    const float* x       = (const float*)d_in[0];
    const int*   t       = (const int*)  d_in[1];
    const float* fw      = (const float*)d_in[2];
    const float* fb      = (const float*)d_in[3];
    const float* f_gamma = (const float*)d_in[4];
    const float* f_beta  = (const float*)d_in[5];
    const float* f_mean  = (const float*)d_in[6];
    const float* f_var   = (const float*)d_in[7];
    const float* tw1     = (const float*)d_in[8];
    const float* tb1     = (const float*)d_in[9];
    const float* t_gamma = (const float*)d_in[10];
    const float* t_beta  = (const float*)d_in[11];
    const float* t_mean  = (const float*)d_in[12];
    const float* t_var   = (const float*)d_in[13];
    const float* tw2     = (const float*)d_in[14];
    const float* tb2     = (const float*)d_in[15];

    float* ws   = (float*)d_ws;
    float* outp = (float*)d_out;
    const int B = in_sizes[0] / 128;   // 262144

    tarnet_pre<<<2, 256, 0, stream>>>(fw, fb, f_gamma, f_beta, f_mean, f_var,
                                      tw1, tb1, t_gamma, t_beta, t_mean, t_var,
                                      tw2, tb2, ws);
    tarnet_main<<<B / 128, 256, 0, stream>>>(x, t, ws, outp);
}